// Round 2
// baseline (835.189 us; speedup 1.0000x reference)
//
#include <hip/hip_runtime.h>
#include <cmath>

// SpikeFP32GELUExact: [B,S,32] {0,1} fp32 pulse bits -> decode IEEE-754 fp32
// -> exact fp64 tanh-GELU (reference op order) -> fp32 -> re-encode pulses.
//
// Round 2: value-per-lane transpose. Round 1 kept 8 lanes per value, so each
// wave issued one fp64 GELU sequence per 8 values -> compute-bound (803 us,
// ~4x over the HBM roofline; fp64 wave-instrs are ~8 cyc on MI355X).
// Here a wave loads 512 consecutive float4s in 8 fully-coalesced iterations;
// a width-8 shfl_xor OR-butterfly assembles whole 32-bit words and lane L
// keeps the word of value v_L = (L&7)*8 + (L>>3). One GELU sequence now
// serves 64 distinct values (8x less fp64 per byte) -> memory-bound.
//
// Bit conventions: pulse i of a value <-> bit (31-i). float4 index f holds
// pulses [4f,4f+4) => value f>>3, part g=f&7, bits (31-4g)..(28-4g).
// Pulses are exactly 0.0f/1.0f, so bit 23 of their IEEE encoding IS the bit.

__global__ __launch_bounds__(256) void spike_gelu_kernel(
    const float4* __restrict__ in, float4* __restrict__ out, long n4) {
  const int lane = (int)(threadIdx.x & 63u);
  const long wid = (long)blockIdx.x * (blockDim.x >> 6) + (threadIdx.x >> 6);
  const long base = wid * 512;  // 512 float4 = 64 values per wave
  if (base >= n4) return;

  const unsigned g = (unsigned)lane & 7u;   // part index within a value
  const unsigned k = (unsigned)lane >> 3;   // 8-lane group id
  const unsigned s = 28u - 4u * g;          // nibble shift for part g

  // ---- decode: 8 coalesced float4 loads; butterfly-OR to full words.
  // After iteration j, every lane of group k holds the word of value j*8+k;
  // lane with g==j keeps it -> lane L ends with value (L&7)*8 + (L>>3).
  unsigned myword = 0u;
#pragma unroll
  for (int j = 0; j < 8; ++j) {
    float4 p = in[base + (long)(j * 64 + lane)];
    unsigned nib = (((__float_as_uint(p.x) >> 23) & 1u) << 3) |
                   (((__float_as_uint(p.y) >> 23) & 1u) << 2) |
                   (((__float_as_uint(p.z) >> 23) & 1u) << 1) |
                   (((__float_as_uint(p.w) >> 23) & 1u));
    unsigned u = nib << s;
    u |= __shfl_xor(u, 1, 8);
    u |= __shfl_xor(u, 2, 8);
    u |= __shfl_xor(u, 4, 8);
    if ((int)g == j) myword = u;
  }

  // ---- exact fp64 GELU, one distinct value per lane. Contraction OFF:
  // the reference rounds each mul/add separately; an fma would change bits.
  float xf = __uint_as_float(myword);
  double y;
  {
#pragma clang fp contract(off)
    double x = (double)xf;
    double x_cubed = (x * x) * x;
    double inner = x + 0.044715 * x_cubed;
    double two_z = 2.0 * (0.7978845608028654 * inner);
    double e = exp(two_z);
    double th = (e - 1.0) / (e + 1.0);
    y = 0.5 * (x * (1.0 + th));
  }
  float yf = (float)y;
  unsigned r = __float_as_uint(yf);

  // ---- encode: gather the word of value j*8+k from lane k*8+j, emit the
  // nibble for part g as four 0.0/1.0 floats, fully-coalesced stores.
#pragma unroll
  for (int j = 0; j < 8; ++j) {
    unsigned w = __shfl((int)r, (int)(k * 8u + (unsigned)j), 64);
    float4 o;
    o.x = (float)((w >> (s + 3u)) & 1u);
    o.y = (float)((w >> (s + 2u)) & 1u);
    o.z = (float)((w >> (s + 1u)) & 1u);
    o.w = (float)((w >> s) & 1u);
    out[base + (long)(j * 64 + lane)] = o;
  }
}

extern "C" void kernel_launch(void* const* d_in, const int* in_sizes, int n_in,
                              void* d_out, int out_size, void* d_ws, size_t ws_size,
                              hipStream_t stream) {
  const float4* in = (const float4*)d_in[0];
  float4* out = (float4*)d_out;
  long n4 = (long)in_sizes[0] / 4;  // 2^25 float4s
  const int block = 256;            // 4 waves * 512 float4 = 2048 float4/block
  long grid = (n4 + 2048 - 1) / 2048;
  spike_gelu_kernel<<<(int)grid, block, 0, stream>>>(in, out, n4);
}

// Round 4
// 807.194 us; speedup vs baseline: 1.0347x; 1.0347x over previous
//
#include <hip/hip_runtime.h>
#include <cmath>

// SpikeFP32GELUExact: [B,S,32] {0,1} fp32 pulse bits -> decode IEEE-754 fp32
// -> exact fp64 tanh-GELU (reference op order) -> fp32 -> re-encode pulses.
//
// Round 4 = round 3 with the compile fix: __builtin_nontemporal_load/store
// requires native clang vector types, not HIP_vector_type structs. Use
// ext_vector_type(4) typedefs (lower to global_load/store_dwordx4 + nt).
//
// Evidence from r1/r2: bench dur_us (~835) includes ~550-600us of harness
// reset traffic (338-346us fillBuffer dispatches dominate rocprof top-5; our
// kernel never appears, so it is <338us). Kernel roofline: 1.07GB / 6.3TB/s
// ~= 170us. This round: max MLP (all 8 loads before any dependent work),
// nontemporal streaming, launch_bounds(256,4), cheap bit-spread encode.
//
// Bit conventions: pulse i of a value <-> bit (31-i). float4 index f holds
// pulses [4f,4f+4) => value f>>3, part g=f&7, bits (31-4g)..(28-4g).
// Pulses are exactly 0.0f/1.0f, so bit 23 of the IEEE encoding IS the bit.

typedef unsigned int u32x4 __attribute__((ext_vector_type(4)));
typedef float f32x4 __attribute__((ext_vector_type(4)));

__global__ __launch_bounds__(256, 4) void spike_gelu_kernel(
    const u32x4* __restrict__ in, f32x4* __restrict__ out, long n4) {
  const int lane = (int)(threadIdx.x & 63u);
  const long wid = (long)blockIdx.x * (blockDim.x >> 6) + (threadIdx.x >> 6);
  const long base = wid * 512;  // 512 float4 = 64 values per wave
  if (base >= n4) return;

  const unsigned g = (unsigned)lane & 7u;   // part index within a value
  const unsigned k = (unsigned)lane >> 3;   // 8-lane group id
  const unsigned s = 28u - 4u * g;          // nibble shift for part g

  // ---- load phase: all 8 coalesced 16B loads in flight before any use.
  u32x4 p[8];
#pragma unroll
  for (int j = 0; j < 8; ++j)
    p[j] = __builtin_nontemporal_load(&in[base + (long)(j * 64 + lane)]);

  // ---- decode: pack nibble (bit 23 of each pulse), butterfly-OR across the
  // aligned 8-lane group; lane L keeps the word of value (L&7)*8 + (L>>3).
  unsigned myword = 0u;
#pragma unroll
  for (int j = 0; j < 8; ++j) {
    unsigned nib = (((p[j].x >> 23) & 1u) << 3) | (((p[j].y >> 23) & 1u) << 2) |
                   (((p[j].z >> 23) & 1u) << 1) | ((p[j].w >> 23) & 1u);
    unsigned u = nib << s;
    u |= __shfl_xor(u, 1, 8);
    u |= __shfl_xor(u, 2, 8);
    u |= __shfl_xor(u, 4, 8);
    myword = ((int)g == j) ? u : myword;
  }

  // ---- exact fp64 GELU, one distinct value per lane. Contraction OFF:
  // the reference rounds each mul/add separately; an fma would change bits.
  float xf = __uint_as_float(myword);
  double y;
  {
#pragma clang fp contract(off)
    double x = (double)xf;
    double x_cubed = (x * x) * x;
    double inner = x + 0.044715 * x_cubed;
    double two_z = 2.0 * (0.7978845608028654 * inner);
    double e = exp(two_z);
    double th = (e - 1.0) / (e + 1.0);
    y = 0.5 * (x * (1.0 + th));
  }
  unsigned r = __float_as_uint((float)y);

  // ---- encode: gather word of value j*8+k from lane k*8+j; spread the
  // 4-bit nibble to 4 bytes ((n*0x204081)&0x01010101: bit b -> byte b),
  // then byte->float (v_cvt_f32_ubyteN). Coalesced nontemporal stores.
#pragma unroll
  for (int j = 0; j < 8; ++j) {
    unsigned w = (unsigned)__shfl((int)r, (int)(k * 8u + (unsigned)j), 64);
    unsigned nib = (w >> s) & 0xFu;
    unsigned spread = (nib * 0x00204081u) & 0x01010101u;
    f32x4 o;
    o.x = (float)((spread >> 24) & 0xFFu);  // nibble bit 3 -> pulse 4g+0
    o.y = (float)((spread >> 16) & 0xFFu);  // nibble bit 2 -> pulse 4g+1
    o.z = (float)((spread >> 8) & 0xFFu);   // nibble bit 1 -> pulse 4g+2
    o.w = (float)(spread & 0xFFu);          // nibble bit 0 -> pulse 4g+3
    __builtin_nontemporal_store(o, &out[base + (long)(j * 64 + lane)]);
  }
}

extern "C" void kernel_launch(void* const* d_in, const int* in_sizes, int n_in,
                              void* d_out, int out_size, void* d_ws, size_t ws_size,
                              hipStream_t stream) {
  const u32x4* in = (const u32x4*)d_in[0];
  f32x4* out = (f32x4*)d_out;
  long n4 = (long)in_sizes[0] / 4;  // 2^25 float4s
  const int block = 256;            // 4 waves * 512 float4 = 2048 float4/block
  long grid = (n4 + 2048 - 1) / 2048;
  spike_gelu_kernel<<<(int)grid, block, 0, stream>>>(in, out, n4);
}